// Round 5
// baseline (238.524 us; speedup 1.0000x reference)
//
#include <hip/hip_runtime.h>
#include <math.h>

#define B_ 2
#define C_ 32
#define H_ 256
#define W_ 256
#define HW_ (H_ * W_)
#define EPS 1e-20f
#define REC 48        // floats per per-channel weight record (16B-aligned)
#define NW2 1570      // 32*REC + 32 bias + 2 inv-sums

// P layout (floats):
//   rec[c] at P[c*48]: [0..8] sw[c][j]; [10] w_g[c]; [11] 1/(1+w_g[c]);
//                      [12..43] cwT[c][o] = softplus(channel_weight[o][c])
//   P[1536..1567] bias[o]; P[1568] 1/sum(sw); P[1569] 1/sum(cw)

__device__ __forceinline__ float softplus_f(float x) {
  return fmaxf(x, 0.f) + log1pf(expf(-fabsf(x)));
}

__global__ void prep_kernel(const float* __restrict__ w_grad,
                            const float* __restrict__ sweight,
                            const float* __restrict__ cweight,
                            const float* __restrict__ bias,
                            float* __restrict__ P) {
  const int t = threadIdx.x;  // 1024 threads, 1 block
  float swv = 0.f, cwv = 0.f;
  if (t < 288) {
    float s = softplus_f(sweight[t]);
    P[(t / 9) * REC + (t % 9)] = s;
    swv = s;
  }
  {
    float s = softplus_f(cweight[t]);  // t = o*32 + i
    P[(t & 31) * REC + 12 + (t >> 5)] = s;
    cwv = s;
  }
  if (t < 32) {
    float wg = softplus_f(w_grad[t]);
    P[t * REC + 10] = wg;
    P[t * REC + 11] = 1.f / (1.f + wg);
    P[1536 + t] = bias[t];
  }
#pragma unroll
  for (int off = 32; off > 0; off >>= 1) {
    swv += __shfl_down(swv, off);
    cwv += __shfl_down(cwv, off);
  }
  __shared__ float s_sw[16], s_cw[16];
  const int wave = t >> 6, lane = t & 63;
  if (lane == 0) { s_sw[wave] = swv; s_cw[wave] = cwv; }
  __syncthreads();
  if (t == 0) {
    float a = 0.f, b = 0.f;
#pragma unroll
    for (int i = 0; i < 16; ++i) { a += s_sw[i]; b += s_cw[i]; }
    P[1568] = 1.f / a;
    P[1569] = 1.f / b;
  }
}

// Block = 256 threads = 4 waves. Tile = 16x4 = 64 pixels; the 4 waves split
// the 32 channels (8 each) in phase 1 and the 32 outputs (8 each) in phase 2.
// Grid = 16 wtiles * 64 htiles * 2 b = 2048 blocks -> 8192 waves = full chip.
__global__ __launch_bounds__(256, 4) void fused_kernel(
    const float* __restrict__ d, const float* __restrict__ cd,
    const float* __restrict__ gx, const float* __restrict__ cgx,
    const float* __restrict__ gy, const float* __restrict__ cgy,
    const float* __restrict__ P, float* __restrict__ out) {
  __shared__ float2 pairs[C_][64];  // {cd_spatial, cd_spatial*d_spatial}

  const int t = threadIdx.x;
  const int p = t & 63;                                       // pixel in tile
  const int g = __builtin_amdgcn_readfirstlane(t >> 6);       // wave id 0..3

  // XCD-chunked bijective swizzle (2048 % 8 == 0): 256 consecutive works per
  // XCD; consecutive works are vertically-adjacent tiles -> same-L2 halo reuse.
  const int wid = (blockIdx.x & 7) * 256 + (blockIdx.x >> 3);
  const int b = wid >> 10;
  const int rem = wid & 1023;
  const int w = (rem >> 6) * 16 + (p & 15);
  const int h = (rem & 63) * 4 + (p >> 4);

  const int base0 = b * C_ * HW_ + h * W_ + w;
  const bool okl = (w > 0), okr = (w < W_ - 1);
  const bool oku = (h > 0), okd = (h < H_ - 1);
  const float inv_sum_sw = P[1568];

  // ---- phase 1: spatial stage, 8 channels per thread ----
#pragma unroll 1
  for (int c8 = 0; c8 < 8; ++c8) {
    const int c = g * 8 + c8;                 // wave-uniform
    const float* rec = P + c * REC;           // uniform -> s_load path
    const float wg = rec[10], inv1 = rec[11];
    const int base = base0 + c * HW_;

    const float d_c = d[base], cd_c = cd[base];
    const float gx_c = gx[base], cgx_c = cgx[base];
    const float gy_c = gy[base], cgy_c = cgy[base];
    const float cgxgx = cgx_c * gx_c;
    const float cgygy = cgy_c * gy_c;
    const float cgx_eps = cgx_c + EPS;
    const float cgy_eps = cgy_c + EPS;

    // center tap (j=4): g_prop = 0, cg_prop = 0 exactly
    float nom, den;
    {
      const float cdp = cd_c * inv1;
      const float s = rec[4];
      nom = cdp * d_c * s;
      den = cdp * s;
    }
#pragma unroll
    for (int r = 0; r < 3; ++r) {
#pragma unroll
      for (int cc = 0; cc < 3; ++cc) {
        const int dr = r - 1, dc = cc - 1;
        if (dr == 0 && dc == 0) continue;
        // OOB taps contribute exactly 0 (cd_roll=0 -> cd_prop=0): skip.
        const bool ok = (dr < 0 ? oku : dr > 0 ? okd : true) &&
                        (dc < 0 ? okl : dc > 0 ? okr : true);
        if (ok) {
          const int nb = base + dr * W_ + dc;
          const float d_r = d[nb], cd_r = cd[nb];
          float gp, cgp;
          if (dc != 0 && dr != 0) {  // corner: both axes active
            const float gxr = gx[nb], cgxr = cgx[nb];
            const float gyr = gy[nb], cgyr = cgy[nb];
            const float gxp =
                fmaf(cgxr, gxr, cgxgx) * __builtin_amdgcn_rcpf(cgxr + cgx_eps);
            const float gyp =
                fmaf(cgyr, gyr, cgygy) * __builtin_amdgcn_rcpf(cgyr + cgy_eps);
            gp = (dc > 0 ? -gxp : gxp) + (dr > 0 ? -gyp : gyp);
            cgp = 0.25f * ((cgxr + cgx_c) + (cgyr + cgy_c));
          } else if (dc != 0) {  // horizontal tap: x axis only
            const float gxr = gx[nb], cgxr = cgx[nb];
            const float gxp =
                fmaf(cgxr, gxr, cgxgx) * __builtin_amdgcn_rcpf(cgxr + cgx_eps);
            gp = (dc > 0 ? -gxp : gxp);
            cgp = 0.5f * (cgxr + cgx_c);
          } else {  // vertical tap: y axis only
            const float gyr = gy[nb], cgyr = cgy[nb];
            const float gyp =
                fmaf(cgyr, gyr, cgygy) * __builtin_amdgcn_rcpf(cgyr + cgy_eps);
            gp = (dr > 0 ? -gyp : gyp);
            cgp = 0.5f * (cgyr + cgy_c);
          }
          const float dp = d_r * (1.f + gp);
          const float cdp = cd_r * fmaf(wg, cgp, 1.f) * inv1;
          const float s = rec[r * 3 + cc];
          nom = fmaf(cdp * dp, s, nom);
          den = fmaf(cdp, s, den);
        }
      }
    }
    const float cs_c = den * inv_sum_sw;
    const float csds_c = cs_c * (nom * __builtin_amdgcn_rcpf(den + EPS));
    pairs[c][p] = make_float2(cs_c, csds_c);  // 8B/lane, 2-way alias = free
  }

  __syncthreads();

  // ---- phase 2: channel mix, 8 outputs per thread (o = g*8..g*8+7) ----
  const float inv_sum_cw = P[1569];
  float no[8], de[8];
#pragma unroll
  for (int oo = 0; oo < 8; ++oo) { no[oo] = 0.f; de[oo] = 0.f; }

#pragma unroll 4
  for (int i = 0; i < C_; ++i) {
    const float2 pr = pairs[i][p];
    const float* wp = P + i * REC + 12 + g * 8;  // wave-uniform -> s_load
#pragma unroll
    for (int oo = 0; oo < 8; ++oo) {
      const float cwv = wp[oo];
      no[oo] = fmaf(pr.y, cwv, no[oo]);
      de[oo] = fmaf(pr.x, cwv, de[oo]);
    }
  }

#pragma unroll
  for (int oo = 0; oo < 8; ++oo) {
    const int o = g * 8 + oo;
    const int ob = base0 + o * HW_;
    out[ob] = no[oo] * __builtin_amdgcn_rcpf(de[oo] + EPS) + P[1536 + o];
    out[B_ * C_ * HW_ + ob] = de[oo] * inv_sum_cw;
  }
}

extern "C" void kernel_launch(void* const* d_in, const int* in_sizes, int n_in,
                              void* d_out, int out_size, void* d_ws, size_t ws_size,
                              hipStream_t stream) {
  const float* d_   = (const float*)d_in[0];
  const float* cd_  = (const float*)d_in[1];
  const float* gx_  = (const float*)d_in[2];
  const float* cgx_ = (const float*)d_in[3];
  const float* gy_  = (const float*)d_in[4];
  const float* cgy_ = (const float*)d_in[5];
  const float* wgr  = (const float*)d_in[6];
  const float* swt  = (const float*)d_in[7];
  const float* cwt  = (const float*)d_in[8];
  const float* bias = (const float*)d_in[9];
  float* out = (float*)d_out;
  float* P = (float*)d_ws;

  prep_kernel<<<1, 1024, 0, stream>>>(wgr, swt, cwt, bias, P);
  fused_kernel<<<2048, 256, 0, stream>>>(d_, cd_, gx_, cgx_, gy_, cgy_, P, out);
}

// Round 10
// 173.506 us; speedup vs baseline: 1.3747x; 1.3747x over previous
//
#include <hip/hip_runtime.h>
#include <math.h>

#define B_ 2
#define C_ 32
#define H_ 256
#define W_ 256
#define HW_ (H_ * W_)
#define EPS 1e-20f
#define REC 48        // floats per per-channel weight record
// LDS staging geometry: 32x8 pixel tile, halo'd + float4-aligned
#define TW 32
#define TH 8
#define SROWS 10               // TH + 2
#define SCOLS 40               // TW + 8 (cols w0-4 .. w0+35, 16B-aligned)
#define SC4 (SCOLS / 4)        // 10 float4 per staged row
#define PLANE_F (SROWS * SCOLS)  // 400 floats per plane
#define CH_F (6 * PLANE_F)       // 2400 floats per channel buffer
#define NSLOT (6 * SROWS * SC4)  // 600 float4 staging slots

// P layout (floats):
//   rec[c] at P[c*48]: [0..8] sw[c][j]; [10] w_g[c]; [11] 1/(1+w_g[c]);
//                      [12..43] cwT[c][o] = softplus(channel_weight[o][c])
//   P[1536..1567] bias[o]; P[1568] 1/sum(sw); P[1569] 1/sum(cw)

__device__ __forceinline__ float softplus_f(float x) {
  return fmaxf(x, 0.f) + log1pf(expf(-fabsf(x)));
}

__global__ void prep_kernel(const float* __restrict__ w_grad,
                            const float* __restrict__ sweight,
                            const float* __restrict__ cweight,
                            const float* __restrict__ bias,
                            float* __restrict__ P) {
  const int t = threadIdx.x;  // 1024 threads, 1 block
  float swv = 0.f, cwv = 0.f;
  if (t < 288) {
    float s = softplus_f(sweight[t]);
    P[(t / 9) * REC + (t % 9)] = s;
    swv = s;
  }
  {
    float s = softplus_f(cweight[t]);  // t = o*32 + i
    P[(t & 31) * REC + 12 + (t >> 5)] = s;
    cwv = s;
  }
  if (t < 32) {
    float wg = softplus_f(w_grad[t]);
    P[t * REC + 10] = wg;
    P[t * REC + 11] = 1.f / (1.f + wg);
    P[1536 + t] = bias[t];
  }
#pragma unroll
  for (int off = 32; off > 0; off >>= 1) {
    swv += __shfl_down(swv, off);
    cwv += __shfl_down(cwv, off);
  }
  __shared__ float s_sw[16], s_cw[16];
  const int wave = t >> 6, lane = t & 63;
  if (lane == 0) { s_sw[wave] = swv; s_cw[wave] = cwv; }
  __syncthreads();
  if (t == 0) {
    float a = 0.f, b = 0.f;
#pragma unroll
    for (int i = 0; i < 16; ++i) { a += s_sw[i]; b += s_cw[i]; }
    P[1568] = 1.f / a;
    P[1569] = 1.f / b;
  }
}

// Block = 256 threads = 32x8 pixel tile, 1 px/thread, all 32 channels/thread.
// Per channel: block stages the 6 input planes' halo'd tile into LDS with
// float4 loads (600 float4 vs 11776 scalar dwords -> ~20x fewer VMEM instrs),
// double-buffered: loads for c+1 issue BEFORE compute(c) (T14 issue-early/
// write-late), ds_write lands after, one barrier per channel.
// Grid = 512 blocks (2/CU) with XCD-chunked swizzle.
__global__ __launch_bounds__(256, 2) void fused_kernel(
    const float* __restrict__ d, const float* __restrict__ cd,
    const float* __restrict__ gx, const float* __restrict__ cgx,
    const float* __restrict__ gy, const float* __restrict__ cgy,
    const float* __restrict__ P, float* __restrict__ out) {
  __shared__ float sbuf[2 * CH_F];  // 19.2 KB

  const int t = threadIdx.x;
  const int x = t & 31, y = t >> 5;

  // XCD-chunked bijective swizzle (512 % 8 == 0): consecutive works are
  // vertically-adjacent tiles -> same-XCD L2 reuse of halo rows.
  const int wid = (blockIdx.x & 7) * 64 + (blockIdx.x >> 3);
  const int b = wid >> 8;
  const int rem = wid & 255;
  const int w0 = (rem >> 5) * TW;
  const int h0 = (rem & 31) * TH;
  const int w = w0 + x, h = h0 + y;

  // ---- staging slots: 600 float4; thread t owns slots t, t+256, t+512 ----
  const float* sp[3];
  int soff[3];
  bool sv[3], sw_ok[3];
#pragma unroll
  for (int k = 0; k < 3; ++k) {
    const int s = t + 256 * k;
    sw_ok[k] = (s < NSLOT);
    if (s < NSLOT) {
      const int p = s / (SROWS * SC4);    // plane 0..5
      const int r10 = (s / SC4) % SROWS;  // staged row 0..9
      const int c10 = s % SC4;            // float4 col 0..9
      const int grow = h0 - 1 + r10;
      const int gcol = w0 - 4 + c10 * 4;  // multiple of 4; f4 fully in/out
      sv[k] = (grow >= 0) && (grow < H_) && ((unsigned)gcol < (unsigned)W_);
      const float* pb = (p == 0) ? d : (p == 1) ? cd : (p == 2) ? gx
                        : (p == 3) ? cgx : (p == 4) ? gy : cgy;
      sp[k] = pb + b * C_ * HW_ + grow * W_ + gcol;  // channel 0 address
      soff[k] = p * PLANE_F + r10 * SCOLS + c10 * 4;
    } else {
      sv[k] = false;
      sp[k] = d;
      soff[k] = 0;
    }
  }

  // ---- prologue: stage channel 0 into buffer 0 ----
  float4 rs[3];
#pragma unroll
  for (int k = 0; k < 3; ++k)
    rs[k] = sv[k] ? *(const float4*)sp[k] : make_float4(0.f, 0.f, 0.f, 0.f);
#pragma unroll
  for (int k = 0; k < 3; ++k)
    if (sw_ok[k]) *(float4*)(&sbuf[soff[k]]) = rs[k];
  __syncthreads();

  const bool okl = (w > 0), okr = (w < W_ - 1);
  const bool oku = (h > 0), okd = (h < H_ - 1);
  const float inv_sum_sw = P[1568];

  float no[C_], de[C_];
#pragma unroll
  for (int o = 0; o < C_; ++o) { no[o] = 0.f; de[o] = 0.f; }

  const int cro = (y + 1) * SCOLS + (x + 4);  // center offset within a plane

#pragma unroll 1
  for (int c = 0; c < C_; ++c) {
    // T14 issue-early: next channel's global loads start before compute(c)
    if (c + 1 < C_) {
#pragma unroll
      for (int k = 0; k < 3; ++k) {
        sp[k] += HW_;
        rs[k] = sv[k] ? *(const float4*)sp[k] : make_float4(0.f, 0.f, 0.f, 0.f);
      }
    }

    const float* Bf = sbuf + (c & 1) * CH_F;
    const float* rec = P + c * REC;  // c uniform -> s_load path
    const float wg = rec[10], inv1 = rec[11];

    const float d_c = Bf[0 * PLANE_F + cro];
    const float cd_c = Bf[1 * PLANE_F + cro];
    const float gx_c = Bf[2 * PLANE_F + cro];
    const float cgx_c = Bf[3 * PLANE_F + cro];
    const float gy_c = Bf[4 * PLANE_F + cro];
    const float cgy_c = Bf[5 * PLANE_F + cro];
    const float cgxgx = cgx_c * gx_c;
    const float cgygy = cgy_c * gy_c;
    const float cgx_eps = cgx_c + EPS;
    const float cgy_eps = cgy_c + EPS;

    // center tap (j=4): g_prop = 0, cg_prop = 0 exactly
    float nom, den;
    {
      const float cdp = cd_c * inv1;
      const float s = rec[4];
      nom = cdp * d_c * s;
      den = cdp * s;
    }
#pragma unroll
    for (int r = 0; r < 3; ++r) {
#pragma unroll
      for (int cc = 0; cc < 3; ++cc) {
        const int dr = r - 1, dc = cc - 1;
        if (dr == 0 && dc == 0) continue;
        // OOB taps contribute exactly 0 (cd_roll=0 -> cd_prop=0): skip.
        const bool ok = (dr < 0 ? oku : dr > 0 ? okd : true) &&
                        (dc < 0 ? okl : dc > 0 ? okr : true);
        if (ok) {
          const int tb = cro + dr * SCOLS + dc;  // literal immediate offsets
          const float d_r = Bf[0 * PLANE_F + tb];
          const float cd_r = Bf[1 * PLANE_F + tb];
          float gp, cgp;
          if (dc != 0 && dr != 0) {  // corner: both axes active
            const float gxr = Bf[2 * PLANE_F + tb], cgxr = Bf[3 * PLANE_F + tb];
            const float gyr = Bf[4 * PLANE_F + tb], cgyr = Bf[5 * PLANE_F + tb];
            const float gxp =
                fmaf(cgxr, gxr, cgxgx) * __builtin_amdgcn_rcpf(cgxr + cgx_eps);
            const float gyp =
                fmaf(cgyr, gyr, cgygy) * __builtin_amdgcn_rcpf(cgyr + cgy_eps);
            gp = (dc > 0 ? -gxp : gxp) + (dr > 0 ? -gyp : gyp);
            cgp = 0.25f * ((cgxr + cgx_c) + (cgyr + cgy_c));
          } else if (dc != 0) {  // horizontal tap: x axis only
            const float gxr = Bf[2 * PLANE_F + tb], cgxr = Bf[3 * PLANE_F + tb];
            const float gxp =
                fmaf(cgxr, gxr, cgxgx) * __builtin_amdgcn_rcpf(cgxr + cgx_eps);
            gp = (dc > 0 ? -gxp : gxp);
            cgp = 0.5f * (cgxr + cgx_c);
          } else {  // vertical tap: y axis only
            const float gyr = Bf[4 * PLANE_F + tb], cgyr = Bf[5 * PLANE_F + tb];
            const float gyp =
                fmaf(cgyr, gyr, cgygy) * __builtin_amdgcn_rcpf(cgyr + cgy_eps);
            gp = (dr > 0 ? -gyp : gyp);
            cgp = 0.5f * (cgyr + cgy_c);
          }
          const float dp = d_r * (1.f + gp);
          const float cdp = cd_r * fmaf(wg, cgp, 1.f) * inv1;
          const float s = rec[r * 3 + cc];
          nom = fmaf(cdp * dp, s, nom);
          den = fmaf(cdp, s, den);
        }
      }
    }
    const float cs_c = den * inv_sum_sw;
    const float csds_c = cs_c * (nom * __builtin_amdgcn_rcpf(den + EPS));

    // channel mix as outer-product accumulation; weights via s_load
    const float* wp = rec + 12;
#pragma unroll
    for (int oo = 0; oo < C_; ++oo) {
      const float cwv = wp[oo];
      no[oo] = fmaf(csds_c, cwv, no[oo]);
      de[oo] = fmaf(cs_c, cwv, de[oo]);
    }

    // T14 write-late: staged regs -> other buffer (vmcnt wait inserted here)
    if (c + 1 < C_) {
      float* Wf = sbuf + ((c + 1) & 1) * CH_F;
#pragma unroll
      for (int k = 0; k < 3; ++k)
        if (sw_ok[k]) *(float4*)(&Wf[soff[k]]) = rs[k];
    }
    __syncthreads();
  }

  // ---- epilogue: normalize + bias, coalesced stores ----
  const float inv_sum_cw = P[1569];
  const int base0 = b * C_ * HW_ + h * W_ + w;
#pragma unroll
  for (int o = 0; o < C_; ++o) {
    const int ob = base0 + o * HW_;
    out[ob] = no[o] * __builtin_amdgcn_rcpf(de[o] + EPS) + P[1536 + o];
    out[B_ * C_ * HW_ + ob] = de[o] * inv_sum_cw;
  }
}

extern "C" void kernel_launch(void* const* d_in, const int* in_sizes, int n_in,
                              void* d_out, int out_size, void* d_ws, size_t ws_size,
                              hipStream_t stream) {
  const float* d_   = (const float*)d_in[0];
  const float* cd_  = (const float*)d_in[1];
  const float* gx_  = (const float*)d_in[2];
  const float* cgx_ = (const float*)d_in[3];
  const float* gy_  = (const float*)d_in[4];
  const float* cgy_ = (const float*)d_in[5];
  const float* wgr  = (const float*)d_in[6];
  const float* swt  = (const float*)d_in[7];
  const float* cwt  = (const float*)d_in[8];
  const float* bias = (const float*)d_in[9];
  float* out = (float*)d_out;
  float* P = (float*)d_ws;

  prep_kernel<<<1, 1024, 0, stream>>>(wgr, swt, cwt, bias, P);
  fused_kernel<<<512, 256, 0, stream>>>(d_, cd_, gx_, cgx_, gy_, cgy_, P, out);
}